// Round 7
// baseline (381.959 us; speedup 1.0000x reference)
//
#include <hip/hip_runtime.h>
#include <hip/hip_bf16.h>

#define NB 16
#define ND 256
#define NL 1024
#define NHH 8
#define NDK 32
#define NKW 7
#define NCONV 4
#define NPB (ND*NL)

constexpr float LN_EPS = 1e-5f;

typedef __attribute__((ext_vector_type(4))) float f32x4;
typedef __attribute__((ext_vector_type(4))) short bf16x4;
typedef __attribute__((ext_vector_type(8))) short bf16x8;

__device__ __forceinline__ short bf16s(float f){   // RNE via HW conversion (pairs into cvt_pk)
  return (short)__builtin_bit_cast(unsigned short, __float2bfloat16(f));
}
__device__ __forceinline__ float b2f(short s){
  return __builtin_bit_cast(float, ((unsigned)(unsigned short)s) << 16);
}

// ---------------- LN stats: 8 bins x 128B apart per (slot,b) ----------------
__device__ __forceinline__ void ln_ab(const float* st, int slot, int b, float& mean, float& rstd){
  float s = 0.f, ss = 0.f;
  #pragma unroll
  for(int bin=0;bin<8;bin++){
    const float* p = st + ((size_t)((slot*NB+b)*8+bin))*32;
    s += p[0]; ss += p[1];
  }
  mean = s * (1.0f/NPB);
  float var = ss * (1.0f/NPB) - mean*mean;
  rstd = rsqrtf(var + LN_EPS);
}

__device__ __forceinline__ void stats_reduce(float s, float ss, float* stats, int slot, int b, int bin){
  __shared__ float red[8];
  #pragma unroll
  for(int o=32;o>0;o>>=1){ s += __shfl_down(s,o); ss += __shfl_down(ss,o); }
  int lane = threadIdx.x & 63, w = threadIdx.x >> 6;
  if(lane==0){ red[w*2]=s; red[w*2+1]=ss; }
  __syncthreads();
  if(threadIdx.x==0){
    float* p = stats + ((size_t)((slot*NB+b)*8+bin))*32;
    atomicAdd(&p[0], red[0]+red[2]+red[4]+red[6]);
    atomicAdd(&p[1], red[1]+red[3]+red[5]+red[7]);
  }
}

// ---------------- one-shot prep ----------------
__global__ __launch_bounds__(256) void k_prep(const float* __restrict__ pw_w, const float* __restrict__ fc_w,
    const float* __restrict__ Wo, const float* __restrict__ Wq, const float* __restrict__ Wk,
    const float* __restrict__ Wv, const float* __restrict__ g, const float* __restrict__ btab,
    const float* __restrict__ dw_w,
    short* __restrict__ Wpwb, short* __restrict__ Wfcb, short* __restrict__ Wob, short* __restrict__ Wcat,
    short* __restrict__ gT, short* __restrict__ bT, float* __restrict__ postab, float* __restrict__ wTt){
  __shared__ float T[64][65];
  int blk = blockIdx.x, tid = threadIdx.x;
  if(blk < 256){                     // pw_w -> bf16
    int idx = blk*1024 + tid*4;
    f32x4 v = *(const f32x4*)(pw_w + idx);
    bf16x4 o;
    #pragma unroll
    for(int j=0;j<4;j++) o[j] = bf16s(v[j]);
    *(bf16x4*)(Wpwb + idx) = o;
  } else if(blk < 320){              // fc_w -> bf16
    int idx = (blk-256)*1024 + tid*4;
    f32x4 v = *(const f32x4*)(fc_w + idx);
    bf16x4 o;
    #pragma unroll
    for(int j=0;j<4;j++) o[j] = bf16s(v[j]);
    *(bf16x4*)(Wfcb + idx) = o;
  } else if(blk < 384){              // Wo[d][e] -> bf16 [e][d]
    int idx = (blk-320)*1024 + tid*4;
    int e = idx >> 8;
    bf16x4 o;
    #pragma unroll
    for(int j=0;j<4;j++){ int d = (idx+j)&255; o[j] = bf16s(Wo[d*ND + e]); }
    *(bf16x4*)(Wob + idx) = o;
  } else if(blk < 576){              // Wq/Wk/Wv -> Wcat[(seg*256+h*32+k)][d]
    int idx = (blk-384)*1024 + tid*4;
    int og = idx >> 8, d = idx & 255;
    int seg = og >> 8, o = og & 255, h = o >> 5, k = o & 31;
    const float* W = (seg==0) ? Wq : ((seg==1) ? Wk : Wv);
    bf16x4 ov;
    #pragma unroll
    for(int j=0;j<4;j++) ov[j] = bf16s(W[((size_t)(h*ND + d + j))*NDK + k]);
    *(bf16x4*)(Wcat + idx) = ov;
  } else if(blk < 832){              // pos table [d][l]
    int d = blk - 576;
    int l = tid*4;
    const float LN1E4_OVER_D = 9.210340371976184f / (float)ND;
    float freq, phase;
    if((d & 1) == 0){ freq =  __expf(-(float)d*LN1E4_OVER_D);      phase = 0.f; }
    else            { freq = -__expf((1.f-(float)d)*LN1E4_OVER_D); phase = 1.5707963267948966f; }
    f32x4 o;
    #pragma unroll
    for(int j=0;j<4;j++) o[j] = sinf((float)(l+j)*freq + phase);
    *(f32x4*)(postab + ((size_t)d<<10) + l) = o;
  } else if(blk < 1600){             // ln_g/ln_b [slot][d][l] -> bf16 [slot][l][d]
    int blk2 = blk - 832;
    int which = blk2 >> 6;
    int tile = blk2 & 63;
    int d0 = (tile & 3) << 6, l0 = (tile >> 2) << 6;
    const float* src = (which < 6) ? (g + (size_t)which*NPB) : (btab + (size_t)(which-6)*NPB);
    short* dst = (which < 6) ? (gT + (size_t)which*NPB) : (bT + (size_t)(which-6)*NPB);
    for(int i=tid;i<1024;i+=256){
      int dd = i>>4, l4 = i&15;
      f32x4 v = *(const f32x4*)(src + (size_t)(d0+dd)*NL + l0 + l4*4);
      #pragma unroll
      for(int j=0;j<4;j++) T[dd][l4*4+j] = v[j];
    }
    __syncthreads();
    for(int i=tid;i<1024;i+=256){
      int ll = i>>4, d4 = i&15;
      bf16x4 o;
      #pragma unroll
      for(int j=0;j<4;j++) o[j] = bf16s(T[d4*4+j][ll]);
      *(bf16x4*)(dst + (size_t)(l0+ll)*ND + d0 + d4*4) = o;
    }
  } else {                           // dw_w [4][256][7] -> wTt [4][7][256]
    int base = (blk-1600)*1024 + tid*4;
    #pragma unroll
    for(int j=0;j<4;j++){
      int idx = base + j;
      if(idx < NCONV*NKW*ND){
        int layer = idx / (NKW*ND), rem = idx % (NKW*ND);
        int q = rem >> 8, d = rem & 255;
        wTt[idx] = dw_w[(layer*ND + d)*NKW + q];
      }
    }
  }
}

// ---------------- x + pos -> Rb [b][l][d] bf16, stats slot 0 ----------------
__global__ __launch_bounds__(256) void k_posadd(const float* __restrict__ x, const float* __restrict__ postab,
                                                short* __restrict__ Rb, float* __restrict__ stats){
  int blk = blockIdx.x;
  int lt = blk & 15, dt = (blk>>4)&3, b = blk>>6;
  int l0 = lt*64, d0 = dt*64;
  __shared__ float T[64][65];
  int tid = threadIdx.x;
  for(int i=tid;i<1024;i+=256){
    int dd = i>>4, l4 = i&15;
    int d = d0+dd;
    f32x4 xv = *(const f32x4*)(x + ((size_t)(b*ND+d)<<10) + l0 + l4*4);
    f32x4 pv = *(const f32x4*)(postab + ((size_t)d<<10) + l0 + l4*4);
    #pragma unroll
    for(int j=0;j<4;j++) T[dd][l4*4+j] = xv[j] + pv[j];
  }
  __syncthreads();
  float s=0.f, ss=0.f;
  for(int i=tid;i<1024;i+=256){
    int ll = i>>4, d4 = i&15;
    bf16x4 o;
    #pragma unroll
    for(int j=0;j<4;j++){
      short rs = bf16s(T[d4*4+j][ll]);
      o[j] = rs;
      float rv = b2f(rs);
      s += rv; ss += rv*rv;
    }
    *(bf16x4*)(Rb + ((size_t)(b*NL+l0+ll)<<8) + d0 + d4*4) = o;
  }
  stats_reduce(s, ss, stats, 0, b, blk & 7);
}

// ---------------- shared MFMA GEMM pieces ----------------
__device__ __forceinline__ void stage_rows_bf16(short* dst, const short* src, int tid, int c){
  for(int i=tid;i<1024;i+=256){
    int rr = i>>4, kk = i&15;
    bf16x8 w = *(const bf16x8*)(src + (size_t)rr*ND + c*128 + kk*8);
    *(bf16x8*)((char*)dst + rr*256 + ((kk*16) ^ ((rr&7)<<4))) = w;
  }
}
__device__ __forceinline__ void stage_act_lnb(short* dst, const short* src, const short* g, const short* bt,
                                              float mean, float rstd, int tid, int c){
  float mr = mean*rstd;
  for(int i=tid;i<1024;i+=256){
    int ll = i>>4, kk = i&15;
    size_t off = (size_t)ll*ND + c*128 + kk*8;
    bf16x8 v = *(const bf16x8*)(src + off);
    bf16x8 gv = *(const bf16x8*)(g + off);
    bf16x8 bv = *(const bf16x8*)(bt + off);
    bf16x8 o;
    #pragma unroll
    for(int j=0;j<8;j++) o[j] = bf16s((b2f(v[j])*rstd - mr)*b2f(gv[j]) + b2f(bv[j]));
    *(bf16x8*)((char*)dst + ll*256 + ((kk*16) ^ ((ll&7)<<4))) = o;
  }
}
__device__ __forceinline__ void mfma_core(const short* As, const short* Bs, int wm, int wn,
                                          int lq, int gg, f32x4 acc[2][2]){
  #pragma unroll
  for(int t=0;t<4;t++){
    bf16x8 a[2], bb[2];
    #pragma unroll
    for(int m=0;m<2;m++){
      int row = wm*32 + m*16 + lq;
      a[m] = *(const bf16x8*)((const char*)As + row*256 + ((t*64 + gg*16) ^ ((row&7)<<4)));
    }
    #pragma unroll
    for(int n=0;n<2;n++){
      int row = wn*32 + n*16 + lq;
      bb[n] = *(const bf16x8*)((const char*)Bs + row*256 + ((t*64 + gg*16) ^ ((row&7)<<4)));
    }
    #pragma unroll
    for(int m=0;m<2;m++)
      #pragma unroll
      for(int n=0;n<2;n++)
        acc[m][n] = __builtin_amdgcn_mfma_f32_16x16x32_bf16(a[m], bb[n], acc[m][n], 0,0,0);
  }
}

// LN'd f32x4 row fragment for conv (0 outside [0,NL))
__device__ __forceinline__ f32x4 lnrow4(const short* __restrict__ Rin, const short* __restrict__ gT,
                                        const short* __restrict__ bT, int b, int lp, int dof,
                                        float rstd, float mr){
  f32x4 t = {0.f,0.f,0.f,0.f};
  if((unsigned)lp < NL){
    bf16x4 v  = *(const bf16x4*)(Rin + ((size_t)(b*NL+lp)<<8) + dof);
    bf16x4 gv = *(const bf16x4*)(gT + ((size_t)lp<<8) + dof);
    bf16x4 bv = *(const bf16x4*)(bT + ((size_t)lp<<8) + dof);
    #pragma unroll
    for(int j=0;j<4;j++) t[j] = (b2f(v[j])*rstd - mr)*b2f(gv[j]) + b2f(bv[j]);
  }
  return t;
}

// ---- fused dwconv+pw: As = conv(LN(Rin)), GEMM with pw weights, relu+bias, Rout = Rin + ., stats ----
__global__ __launch_bounds__(256) void k_cpw(const short* __restrict__ Rin, const short* __restrict__ gT,
    const short* __restrict__ bT, const float* __restrict__ wT, const float* __restrict__ db,
    const short* __restrict__ Wb, const float* __restrict__ bias, short* __restrict__ Rout,
    float* __restrict__ stats, int slot_in, int slot_out){
  int blk = blockIdx.x;
  int lt = blk & 15, et = (blk>>4)&3, b = blk>>6;
  int l0 = lt*64, e0 = et*64;
  int tid = threadIdx.x;
  int w = tid>>6, lane = tid&63, lq = lane&15, gg = lane>>4;
  int wm = w&1, wn = w>>1;
  __shared__ short As[8192], Bs[8192];
  f32x4 acc[2][2];
  acc[0][0]=acc[0][1]=acc[1][0]=acc[1][1] = (f32x4){0.f,0.f,0.f,0.f};
  float mean, rstd; ln_ab(stats, slot_in, b, mean, rstd);
  float mr = mean*rstd;
  int kk4 = tid & 31, lg8 = tid >> 5;   // 4-d group, 8-l group
  const short* Bsrc = Wb + (size_t)e0*ND;
  for(int c=0;c<2;c++){
    __syncthreads();
    {
      int dof = c*128 + kk4*4;
      f32x4 wv[7];
      #pragma unroll
      for(int q=0;q<7;q++) wv[q] = *(const f32x4*)(wT + q*ND + dof);
      f32x4 dbv = *(const f32x4*)(db + dof);
      int lbase = l0 + lg8*8;
      f32x4 ring[7];
      #pragma unroll
      for(int j=0;j<7;j++) ring[j] = lnrow4(Rin, gT, bT, b, lbase-3+j, dof, rstd, mr);
      #pragma unroll
      for(int ol=0;ol<8;ol++){
        f32x4 y = dbv;
        #pragma unroll
        for(int q=0;q<7;q++){
          f32x4 rg = ring[(ol+q)%7];
          #pragma unroll
          for(int j=0;j<4;j++) y[j] += rg[j]*wv[q][j];
        }
        int row = lg8*8 + ol;
        bf16x4 o;
        #pragma unroll
        for(int j=0;j<4;j++) o[j] = bf16s(y[j]);
        *(bf16x4*)((char*)As + row*256 + ((kk4*8) ^ ((row&7)<<4))) = o;
        if(ol<7) ring[ol%7] = lnrow4(Rin, gT, bT, b, lbase+4+ol, dof, rstd, mr);
      }
    }
    stage_rows_bf16(Bs, Bsrc, tid, c);
    __syncthreads();
    mfma_core(As, Bs, wm, wn, lq, gg, acc);
  }
  float s=0.f, ss=0.f;
  #pragma unroll
  for(int n=0;n<2;n++){
    int e = e0 + wn*32 + n*16 + lq;
    float bv = bias[e];
    #pragma unroll
    for(int m=0;m<2;m++){
      #pragma unroll
      for(int r=0;r<4;r++){
        int l = l0 + wm*32 + m*16 + gg*4 + r;
        size_t ix = (size_t)(b*NL+l)*ND + e;
        float v = fmaxf(acc[m][n][r] + bv, 0.f);
        float rr = b2f(Rin[ix]) + v;
        short rs = bf16s(rr);
        Rout[ix] = rs;
        float r2 = b2f(rs);
        s += r2; ss += r2*r2;
      }
    }
  }
  stats_reduce(s, ss, stats, slot_out, b, blk & 7);
}

// ---- fused QKV: LN(Rb) x Wcat -> Qb/Kb bf16 [b][h][l][dk], Vb bf16 V^T [b][h][v][l] ----
__global__ __launch_bounds__(256) void k_qkvf(const short* __restrict__ Rb, const short* __restrict__ gT,
                                              const short* __restrict__ bT, const float* __restrict__ stats,
                                              const short* __restrict__ Wcat, short* __restrict__ Qb,
                                              short* __restrict__ Kb, short* __restrict__ Vb){
  int blk = blockIdx.x;                 // b*192 + et*16 + lt
  int lt = blk & 15;
  int tmp = blk >> 4;
  int et = tmp % 12, b = tmp / 12;
  int l0 = lt*64, e0g = et*64;
  int seg = et >> 2;                    // 0=Q,1=K,2=V
  int tid = threadIdx.x;
  int w = tid>>6, lane = tid&63, lq = lane&15, gg = lane>>4;
  int wm = w&1, wn = w>>1;
  __shared__ short As[8192], Bs[8192];
  f32x4 acc[2][2];
  acc[0][0]=acc[0][1]=acc[1][0]=acc[1][1] = (f32x4){0.f,0.f,0.f,0.f};
  float mean, rstd; ln_ab(stats, 4, b, mean, rstd);
  const short* Asrc = Rb + ((size_t)(b*NL)+l0)*ND;
  const short* gs = gT + (size_t)l0*ND;
  const short* bs = bT + (size_t)l0*ND;
  const short* Bsrc = Wcat + (size_t)e0g*ND;
  for(int c=0;c<2;c++){
    __syncthreads();
    stage_act_lnb(As, Asrc, gs, bs, mean, rstd, tid, c);
    stage_rows_bf16(Bs, Bsrc, tid, c);
    __syncthreads();
    mfma_core(As, Bs, wm, wn, lq, gg, acc);
  }
  #pragma unroll
  for(int n=0;n<2;n++){
    int eo = (et&3)*64 + wn*32 + n*16 + lq;   // 0..255 within segment
    int h = eo>>5, dk = eo&31;
    if(seg < 2){
      short* outp = (seg==0) ? Qb : Kb;
      #pragma unroll
      for(int m=0;m<2;m++){
        #pragma unroll
        for(int r=0;r<4;r++){
          int l = l0 + wm*32 + m*16 + gg*4 + r;
          outp[((size_t)(b*NHH+h)*NL + l)*NDK + dk] = bf16s(acc[m][n][r]);
        }
      }
    } else {
      #pragma unroll
      for(int m=0;m<2;m++){
        int lb = l0 + wm*32 + m*16 + gg*4;
        bf16x4 pk;
        #pragma unroll
        for(int r=0;r<4;r++) pk[r] = bf16s(acc[m][n][r]);
        *(bf16x4*)(Vb + ((size_t)(b*NHH+h)*NDK + dk)*NL + lb) = pk;
      }
    }
  }
}

// ---------------- MFMA flash attention: K/V/mask direct from global (L1/L2), no barriers ----------------
__global__ __launch_bounds__(256) void k_attn(const short* __restrict__ Qb, const short* __restrict__ Kb,
                                              const short* __restrict__ Vt, const int* __restrict__ mask,
                                              short* __restrict__ heads){
  int blk = blockIdx.x;
  // 16 qblks of one (b,h) are 128 apart -> same XCD -> K/V stays in that L2
  int qblk = blk >> 7, bh = blk & 127;
  int b = bh >> 3, h = bh & 7;
  int tid = threadIdx.x;
  int w = tid >> 6, lane = tid & 63;
  int lq = lane & 15, gg = lane >> 4;

  __shared__ short Ps[4][16][40];   // per-wave P scratch; 80B row stride keeps b128 reads 16B-aligned

  int qrow = qblk*64 + w*16 + lq;
  bf16x8 qf = *(const bf16x8*)(Qb + ((size_t)bh*NL + qrow)*NDK + gg*8);

  bf16x8 ones;
  #pragma unroll
  for(int j=0;j<8;j++) ones[j] = (short)0x3F80;   // 1.0bf16

  f32x4 zero = {0.f,0.f,0.f,0.f};
  f32x4 o0 = zero, o1 = zero, o2 = zero;          // o2 = row denominators
  const float scale = 0.17677669529663687f;       // 1/sqrt(32)

  const short* Kbase = Kb + (size_t)bh*NL*NDK;
  const short* V0 = Vt + ((size_t)bh*NDK + lq)*NL;
  const short* V1 = Vt + ((size_t)bh*NDK + 16 + lq)*NL;
  const int* mb = mask + b*NL;

  for(int t0=0; t0<NL; t0+=64){
    #pragma unroll
    for(int sub=0; sub<2; sub++){
      int kb = t0 + sub*32;
      bf16x8 a0 = *(const bf16x8*)(Kbase + (size_t)(kb + lq)*NDK + gg*8);
      bf16x8 a1 = *(const bf16x8*)(Kbase + (size_t)(kb + 16 + lq)*NDK + gg*8);
      int4 mi0 = *(const int4*)(mb + kb + gg*4);
      int4 mi1 = *(const int4*)(mb + kb + 16 + gg*4);
      int ma0[4] = {mi0.x, mi0.y, mi0.z, mi0.w};
      int ma1[4] = {mi1.x, mi1.y, mi1.z, mi1.w};
      f32x4 c0 = __builtin_amdgcn_mfma_f32_16x16x32_bf16(a0, qf, zero, 0, 0, 0);
      f32x4 c1 = __builtin_amdgcn_mfma_f32_16x16x32_bf16(a1, qf, zero, 0, 0, 0);
      bf16x4 p0, p1;
      #pragma unroll
      for(int r=0;r<4;r++){
        float pv0 = __expf(__builtin_fmaf(c0[r], scale, ((float)ma0[r]-1.f)*1e30f));
        p0[r] = bf16s(pv0);
        float pv1 = __expf(__builtin_fmaf(c1[r], scale, ((float)ma1[r]-1.f)*1e30f));
        p1[r] = bf16s(pv1);
      }
      *(bf16x4*)(&Ps[w][lq][gg*4])      = p0;
      *(bf16x4*)(&Ps[w][lq][16 + gg*4]) = p1;
      bf16x8 pf = *(const bf16x8*)(&Ps[w][lq][gg*8]);
      bf16x8 b0 = *(const bf16x8*)(V0 + kb + gg*8);
      bf16x8 b1 = *(const bf16x8*)(V1 + kb + gg*8);
      o0 = __builtin_amdgcn_mfma_f32_16x16x32_bf16(pf, b0, o0, 0, 0, 0);
      o1 = __builtin_amdgcn_mfma_f32_16x16x32_bf16(pf, b1, o1, 0, 0, 0);
      o2 = __builtin_amdgcn_mfma_f32_16x16x32_bf16(pf, ones, o2, 0, 0, 0);
    }
  }
  #pragma unroll
  for(int r=0;r<4;r++){
    int ql = gg*4 + r;
    int qg = qblk*64 + w*16 + ql;
    float mq = (float)mask[b*NL + qg];
    float sc = mq / o2[r];
    short* op = heads + ((size_t)(b*NL + qg))*(NHH*NDK) + h*NDK;
    op[lq]      = bf16s(o0[r]*sc);
    op[16 + lq] = bf16s(o1[r]*sc);
  }
}

// ---- wo: heads(bf16) x Wo^T -> Rb += (in place), stats slot 5 ----
__global__ __launch_bounds__(256) void k_wo(const short* __restrict__ H, const short* __restrict__ Wb,
                                            short* __restrict__ Rb, float* __restrict__ stats){
  int blk = blockIdx.x;
  int lt = blk & 15, et = (blk>>4)&3, b = blk>>6;
  int l0 = lt*64, e0 = et*64;
  int tid = threadIdx.x;
  int w = tid>>6, lane = tid&63, lq = lane&15, gg = lane>>4;
  int wm = w&1, wn = w>>1;
  __shared__ short As[8192], Bs[8192];
  f32x4 acc[2][2];
  acc[0][0]=acc[0][1]=acc[1][0]=acc[1][1] = (f32x4){0.f,0.f,0.f,0.f};
  const short* Asrc = H + ((size_t)(b*NL)+l0)*ND;
  const short* Bsrc = Wb + (size_t)e0*ND;
  for(int c=0;c<2;c++){
    __syncthreads();
    stage_rows_bf16(As, Asrc, tid, c);
    stage_rows_bf16(Bs, Bsrc, tid, c);
    __syncthreads();
    mfma_core(As, Bs, wm, wn, lq, gg, acc);
  }
  float s=0.f, ss=0.f;
  #pragma unroll
  for(int n=0;n<2;n++){
    int e = e0 + wn*32 + n*16 + lq;
    #pragma unroll
    for(int m=0;m<2;m++){
      #pragma unroll
      for(int r=0;r<4;r++){
        int l = l0 + wm*32 + m*16 + gg*4 + r;
        size_t ix = (size_t)(b*NL+l)*ND + e;
        float rr = b2f(Rb[ix]) + acc[m][n][r];
        short rs = bf16s(rr);
        Rb[ix] = rs;
        float r2 = b2f(rs);
        s += r2; ss += r2*r2;
      }
    }
  }
  stats_reduce(s, ss, stats, 5, b, blk & 7);
}

// ---- fc: LN5(Rb) x fc_w -> relu+bias, + Rb -> d_out [b][e][l] fp32 ----
__global__ __launch_bounds__(256) void k_fc(const short* __restrict__ Rb, const short* __restrict__ gT,
                                            const short* __restrict__ bT, const float* __restrict__ stats,
                                            const short* __restrict__ Wb, const float* __restrict__ bias,
                                            float* __restrict__ out){
  int blk = blockIdx.x;
  int lt = blk & 15, et = (blk>>4)&3, b = blk>>6;
  int l0 = lt*64, e0 = et*64;
  int tid = threadIdx.x;
  int w = tid>>6, lane = tid&63, lq = lane&15, gg = lane>>4;
  int wm = w&1, wn = w>>1;
  __shared__ short As[8192], Bs[8192];
  f32x4 acc[2][2];
  acc[0][0]=acc[0][1]=acc[1][0]=acc[1][1] = (f32x4){0.f,0.f,0.f,0.f};
  float mean, rstd; ln_ab(stats, 5, b, mean, rstd);
  const short* Asrc = Rb + ((size_t)(b*NL)+l0)*ND;
  const short* gs = gT + (size_t)l0*ND;
  const short* bs = bT + (size_t)l0*ND;
  const short* Bsrc = Wb + (size_t)e0*ND;
  for(int c=0;c<2;c++){
    __syncthreads();
    stage_act_lnb(As, Asrc, gs, bs, mean, rstd, tid, c);
    stage_rows_bf16(Bs, Bsrc, tid, c);
    __syncthreads();
    mfma_core(As, Bs, wm, wn, lq, gg, acc);
  }
  #pragma unroll
  for(int n=0;n<2;n++){
    int e = e0 + wn*32 + n*16 + lq;
    float bv = bias[e];
    #pragma unroll
    for(int m=0;m<2;m++){
      int lb = l0 + wm*32 + m*16 + gg*4;
      f32x4 ov;
      #pragma unroll
      for(int r=0;r<4;r++){
        float v = fmaxf(acc[m][n][r] + bv, 0.f);
        ov[r] = v + b2f(Rb[(size_t)(b*NL+lb+r)*ND + e]);
      }
      *(f32x4*)(out + (size_t)(b*ND+e)*NL + lb) = ov;
    }
  }
}

extern "C" void kernel_launch(void* const* d_in, const int* in_sizes, int n_in,
                              void* d_out, int out_size, void* d_ws, size_t ws_size,
                              hipStream_t stream){
  const float* x    = (const float*)d_in[0];
  const int*   mask = (const int*)d_in[1];
  const float* dw_w = (const float*)d_in[2];
  const float* dw_b = (const float*)d_in[3];
  const float* pw_w = (const float*)d_in[4];
  const float* pw_b = (const float*)d_in[5];
  const float* ln_g = (const float*)d_in[6];
  const float* ln_b = (const float*)d_in[7];
  const float* Wq   = (const float*)d_in[8];
  const float* Wk   = (const float*)d_in[9];
  const float* Wv   = (const float*)d_in[10];
  const float* Wo   = (const float*)d_in[11];
  const float* fc_w = (const float*)d_in[12];
  const float* fc_b = (const float*)d_in[13];

  float* ws     = (float*)d_ws;
  float* stats  = ws;                          // 98304 floats
  float* postab = ws + 98304;                  // 262144 floats
  short* Rb0    = (short*)(ws + 360448);       // 4194304 bf16 [b][l][d]
  short* Rb1    = (short*)(ws + 2457600);      // 4194304 bf16 (ping-pong)
  short* Hb     = (short*)(ws + 4554752);      // heads
  short* Qb     = (short*)(ws + 6651904);
  short* Kb     = (short*)(ws + 8749056);
  short* Vb     = (short*)(ws + 10846208);
  short* gT     = (short*)(ws + 12943360);     // 6*262144 bf16
  short* bT     = (short*)(ws + 13729792);
  short* Wpwb   = (short*)(ws + 14516224);     // 262144 bf16
  short* Wfcb   = (short*)(ws + 14647296);     // 65536
  short* Wob    = (short*)(ws + 14680064);     // 65536
  short* Wcat   = (short*)(ws + 14712832);     // 196608 bf16
  float* wTt    = ws + 14811136;               // 7168 floats

  hipMemsetAsync(stats, 0, 98304*sizeof(float), stream);
  k_prep<<<1608,256,0,stream>>>(pw_w, fc_w, Wo, Wq, Wk, Wv, ln_g, ln_b, dw_w,
                                Wpwb, Wfcb, Wob, Wcat, gT, bT, postab, wTt);
  k_posadd<<<1024,256,0,stream>>>(x, postab, Rb0, stats);
  short* Pin = Rb0;
  short* Pout = Rb1;
  for(int i=0;i<NCONV;i++){
    k_cpw<<<1024,256,0,stream>>>(Pin, gT + (size_t)i*NPB, bT + (size_t)i*NPB,
                                 wTt + (size_t)i*NKW*ND, dw_b + i*ND,
                                 Wpwb + (size_t)i*65536, pw_b + i*ND,
                                 Pout, stats, i, i+1);
    short* t = Pin; Pin = Pout; Pout = t;
  }
  // after 4 layers, residual is back in Rb0 (Pin)
  k_qkvf<<<3072,256,0,stream>>>(Pin, gT + (size_t)4*NPB, bT + (size_t)4*NPB, stats, Wcat, Qb, Kb, Vb);
  k_attn<<<2048,256,0,stream>>>(Qb, Kb, Vb, mask, Hb);
  k_wo<<<1024,256,0,stream>>>(Hb, Wob, Pin, stats);
  k_fc<<<1024,256,0,stream>>>(Pin, gT + (size_t)5*NPB, bT + (size_t)5*NPB, stats, Wfcb, fc_b, (float*)d_out);
}

// Round 8
// 299.548 us; speedup vs baseline: 1.2751x; 1.2751x over previous
//
#include <hip/hip_runtime.h>
#include <hip/hip_bf16.h>

#define NB 16
#define ND 256
#define NL 1024
#define NHH 8
#define NDK 32
#define NKW 7
#define NCONV 4
#define NPB (ND*NL)

constexpr float LN_EPS = 1e-5f;

typedef __attribute__((ext_vector_type(4))) float f32x4;
typedef __attribute__((ext_vector_type(4))) short bf16x4;
typedef __attribute__((ext_vector_type(8))) short bf16x8;

__device__ __forceinline__ short bf16s(float f){   // RNE via HW conversion (pairs into cvt_pk)
  return (short)__builtin_bit_cast(unsigned short, __float2bfloat16(f));
}
__device__ __forceinline__ float b2f(short s){
  return __builtin_bit_cast(float, ((unsigned)(unsigned short)s) << 16);
}

// ---------------- LN stats: 8 bins x 128B apart per (slot,b) ----------------
__device__ __forceinline__ void ln_ab(const float* st, int slot, int b, float& mean, float& rstd){
  float s = 0.f, ss = 0.f;
  #pragma unroll
  for(int bin=0;bin<8;bin++){
    const float* p = st + ((size_t)((slot*NB+b)*8+bin))*32;
    s += p[0]; ss += p[1];
  }
  mean = s * (1.0f/NPB);
  float var = ss * (1.0f/NPB) - mean*mean;
  rstd = rsqrtf(var + LN_EPS);
}

__device__ __forceinline__ void stats_reduce(float s, float ss, float* stats, int slot, int b, int bin){
  __shared__ float red[8];
  #pragma unroll
  for(int o=32;o>0;o>>=1){ s += __shfl_down(s,o); ss += __shfl_down(ss,o); }
  int lane = threadIdx.x & 63, w = threadIdx.x >> 6;
  if(lane==0){ red[w*2]=s; red[w*2+1]=ss; }
  __syncthreads();
  if(threadIdx.x==0){
    float* p = stats + ((size_t)((slot*NB+b)*8+bin))*32;
    atomicAdd(&p[0], red[0]+red[2]+red[4]+red[6]);
    atomicAdd(&p[1], red[1]+red[3]+red[5]+red[7]);
  }
}

// ---------------- one-shot prep ----------------
__global__ __launch_bounds__(256) void k_prep(const float* __restrict__ pw_w, const float* __restrict__ fc_w,
    const float* __restrict__ Wo, const float* __restrict__ Wq, const float* __restrict__ Wk,
    const float* __restrict__ Wv, const float* __restrict__ g, const float* __restrict__ btab,
    short* __restrict__ Wpwb, short* __restrict__ Wfcb, short* __restrict__ Wob, short* __restrict__ Wcat,
    short* __restrict__ gT, short* __restrict__ bT, float* __restrict__ postab){
  __shared__ float T[64][65];
  int blk = blockIdx.x, tid = threadIdx.x;
  if(blk < 256){                     // pw_w -> bf16
    int idx = blk*1024 + tid*4;
    f32x4 v = *(const f32x4*)(pw_w + idx);
    bf16x4 o;
    #pragma unroll
    for(int j=0;j<4;j++) o[j] = bf16s(v[j]);
    *(bf16x4*)(Wpwb + idx) = o;
  } else if(blk < 320){              // fc_w -> bf16
    int idx = (blk-256)*1024 + tid*4;
    f32x4 v = *(const f32x4*)(fc_w + idx);
    bf16x4 o;
    #pragma unroll
    for(int j=0;j<4;j++) o[j] = bf16s(v[j]);
    *(bf16x4*)(Wfcb + idx) = o;
  } else if(blk < 384){              // Wo[d][e] -> bf16 [e][d]
    int idx = (blk-320)*1024 + tid*4;
    int e = idx >> 8;
    bf16x4 o;
    #pragma unroll
    for(int j=0;j<4;j++){ int d = (idx+j)&255; o[j] = bf16s(Wo[d*ND + e]); }
    *(bf16x4*)(Wob + idx) = o;
  } else if(blk < 576){              // Wq/Wk/Wv -> Wcat[(seg*256+h*32+k)][d]
    int idx = (blk-384)*1024 + tid*4;
    int og = idx >> 8, d = idx & 255;
    int seg = og >> 8, o = og & 255, h = o >> 5, k = o & 31;
    const float* W = (seg==0) ? Wq : ((seg==1) ? Wk : Wv);
    bf16x4 ov;
    #pragma unroll
    for(int j=0;j<4;j++) ov[j] = bf16s(W[((size_t)(h*ND + d + j))*NDK + k]);
    *(bf16x4*)(Wcat + idx) = ov;
  } else if(blk < 832){              // pos table [d][l]
    int d = blk - 576;
    int l = tid*4;
    const float LN1E4_OVER_D = 9.210340371976184f / (float)ND;
    float freq, phase;
    if((d & 1) == 0){ freq =  __expf(-(float)d*LN1E4_OVER_D);      phase = 0.f; }
    else            { freq = -__expf((1.f-(float)d)*LN1E4_OVER_D); phase = 1.5707963267948966f; }
    f32x4 o;
    #pragma unroll
    for(int j=0;j<4;j++) o[j] = sinf((float)(l+j)*freq + phase);
    *(f32x4*)(postab + ((size_t)d<<10) + l) = o;
  } else {                           // ln_g/ln_b [slot][d][l] -> bf16 [slot][l][d]
    int blk2 = blk - 832;
    int which = blk2 >> 6;
    int tile = blk2 & 63;
    int d0 = (tile & 3) << 6, l0 = (tile >> 2) << 6;
    const float* src = (which < 6) ? (g + (size_t)which*NPB) : (btab + (size_t)(which-6)*NPB);
    short* dst = (which < 6) ? (gT + (size_t)which*NPB) : (bT + (size_t)(which-6)*NPB);
    for(int i=tid;i<1024;i+=256){
      int dd = i>>4, l4 = i&15;
      f32x4 v = *(const f32x4*)(src + (size_t)(d0+dd)*NL + l0 + l4*4);
      #pragma unroll
      for(int j=0;j<4;j++) T[dd][l4*4+j] = v[j];
    }
    __syncthreads();
    for(int i=tid;i<1024;i+=256){
      int ll = i>>4, d4 = i&15;
      bf16x4 o;
      #pragma unroll
      for(int j=0;j<4;j++) o[j] = bf16s(T[d4*4+j][ll]);
      *(bf16x4*)(dst + (size_t)(l0+ll)*ND + d0 + d4*4) = o;
    }
  }
}

// ---------------- x + pos -> Rb [b][l][d] bf16, stats slot 0 ----------------
__global__ __launch_bounds__(256) void k_posadd(const float* __restrict__ x, const float* __restrict__ postab,
                                                short* __restrict__ Rb, float* __restrict__ stats){
  int blk = blockIdx.x;
  int lt = blk & 15, dt = (blk>>4)&3, b = blk>>6;
  int l0 = lt*64, d0 = dt*64;
  __shared__ float T[64][65];
  int tid = threadIdx.x;
  for(int i=tid;i<1024;i+=256){
    int dd = i>>4, l4 = i&15;
    int d = d0+dd;
    f32x4 xv = *(const f32x4*)(x + ((size_t)(b*ND+d)<<10) + l0 + l4*4);
    f32x4 pv = *(const f32x4*)(postab + ((size_t)d<<10) + l0 + l4*4);
    #pragma unroll
    for(int j=0;j<4;j++) T[dd][l4*4+j] = xv[j] + pv[j];
  }
  __syncthreads();
  float s=0.f, ss=0.f;
  for(int i=tid;i<1024;i+=256){
    int ll = i>>4, d4 = i&15;
    bf16x4 o;
    #pragma unroll
    for(int j=0;j<4;j++){
      short rs = bf16s(T[d4*4+j][ll]);
      o[j] = rs;
      float rv = b2f(rs);
      s += rv; ss += rv*rv;
    }
    *(bf16x4*)(Rb + ((size_t)(b*NL+l0+ll)<<8) + d0 + d4*4) = o;
  }
  stats_reduce(s, ss, stats, 0, b, blk & 7);
}

// ---------------- depthwise conv, vectorized 4d x 4l per thread, bf16 R ----------------
__global__ __launch_bounds__(256) void k_dwconvT(const short* __restrict__ Rb, const short* __restrict__ gT,
                                                 const short* __restrict__ bT, const float* __restrict__ w7,
                                                 const float* __restrict__ db, const float* __restrict__ stats,
                                                 short* __restrict__ Y, int slot){
  int blk = blockIdx.x;               // b*64 + lblk
  int lblk = blk & 63, b = blk >> 6;
  int tid = threadIdx.x;
  __shared__ float wLds[NKW][ND];
  __shared__ float dbLds[ND];
  for(int i=tid;i<ND*NKW;i+=256){ int d=i/NKW, q=i-d*NKW; wLds[q][d] = w7[i]; }
  dbLds[tid] = db[tid];
  float mean, rstd; ln_ab(stats, slot, b, mean, rstd);
  float mr = mean*rstd;
  __syncthreads();
  int d0 = (tid & 63)*4;
  int l0 = lblk*16 + (tid >> 6)*4;
  f32x4 ln[10];
  #pragma unroll
  for(int i=0;i<10;i++){
    int lp = l0 - 3 + i;
    if(lp >= 0 && lp < NL){
      bf16x4 v = *(const bf16x4*)(Rb + ((size_t)(b*NL+lp)<<8) + d0);
      bf16x4 gv = *(const bf16x4*)(gT + ((size_t)lp<<8) + d0);
      bf16x4 bv = *(const bf16x4*)(bT + ((size_t)lp<<8) + d0);
      f32x4 t;
      #pragma unroll
      for(int j=0;j<4;j++) t[j] = (b2f(v[j])*rstd - mr)*b2f(gv[j]) + b2f(bv[j]);
      ln[i] = t;
    } else ln[i] = (f32x4){0.f,0.f,0.f,0.f};
  }
  f32x4 dbv = *(const f32x4*)(&dbLds[d0]);
  #pragma unroll
  for(int jl=0;jl<4;jl++){
    f32x4 acc = dbv;
    #pragma unroll
    for(int q=0;q<NKW;q++){
      f32x4 wq = *(const f32x4*)(&wLds[q][d0]);
      #pragma unroll
      for(int j=0;j<4;j++) acc[j] += ln[jl+q][j]*wq[j];
    }
    bf16x4 o;
    #pragma unroll
    for(int j=0;j<4;j++) o[j] = bf16s(acc[j]);
    *(bf16x4*)(Y + ((size_t)(b*NL + l0 + jl)<<8) + d0) = o;
  }
}

// ---------------- shared MFMA GEMM pieces ----------------
__device__ __forceinline__ void stage_rows_bf16(short* dst, const short* src, int tid, int c){
  for(int i=tid;i<1024;i+=256){
    int rr = i>>4, kk = i&15;
    bf16x8 w = *(const bf16x8*)(src + (size_t)rr*ND + c*128 + kk*8);
    *(bf16x8*)((char*)dst + rr*256 + ((kk*16) ^ ((rr&7)<<4))) = w;
  }
}
__device__ __forceinline__ void stage_act_lnb(short* dst, const short* src, const short* g, const short* bt,
                                              float mean, float rstd, int tid, int c){
  float mr = mean*rstd;
  for(int i=tid;i<1024;i+=256){
    int ll = i>>4, kk = i&15;
    size_t off = (size_t)ll*ND + c*128 + kk*8;
    bf16x8 v = *(const bf16x8*)(src + off);
    bf16x8 gv = *(const bf16x8*)(g + off);
    bf16x8 bv = *(const bf16x8*)(bt + off);
    bf16x8 o;
    #pragma unroll
    for(int j=0;j<8;j++) o[j] = bf16s((b2f(v[j])*rstd - mr)*b2f(gv[j]) + b2f(bv[j]));
    *(bf16x8*)((char*)dst + ll*256 + ((kk*16) ^ ((ll&7)<<4))) = o;
  }
}
__device__ __forceinline__ void mfma_core(const short* As, const short* Bs, int wm, int wn,
                                          int lq, int gg, f32x4 acc[2][2]){
  #pragma unroll
  for(int t=0;t<4;t++){
    bf16x8 a[2], bb[2];
    #pragma unroll
    for(int m=0;m<2;m++){
      int row = wm*32 + m*16 + lq;
      a[m] = *(const bf16x8*)((const char*)As + row*256 + ((t*64 + gg*16) ^ ((row&7)<<4)));
    }
    #pragma unroll
    for(int n=0;n<2;n++){
      int row = wn*32 + n*16 + lq;
      bb[n] = *(const bf16x8*)((const char*)Bs + row*256 + ((t*64 + gg*16) ^ ((row&7)<<4)));
    }
    #pragma unroll
    for(int m=0;m<2;m++)
      #pragma unroll
      for(int n=0;n<2;n++)
        acc[m][n] = __builtin_amdgcn_mfma_f32_16x16x32_bf16(a[m], bb[n], acc[m][n], 0,0,0);
  }
}

#define GEMM_PROLOGUE() \
  int blk = blockIdx.x; \
  int lt = blk & 15, et = (blk>>4)&3, b = blk>>6; \
  int l0 = lt*64, e0 = et*64; \
  int tid = threadIdx.x; \
  int w = tid>>6, lane = tid&63, lq = lane&15, gg = lane>>4; \
  int wm = w&1, wn = w>>1; \
  __shared__ short As[8192], Bs[8192]; \
  f32x4 acc[2][2]; \
  acc[0][0]=acc[0][1]=acc[1][0]=acc[1][1] = (f32x4){0.f,0.f,0.f,0.f};

// ---- pw: Yb(bf16) x W -> relu+bias, Rb += , stats ----
__global__ __launch_bounds__(256) void k_pw(const short* __restrict__ Y, const short* __restrict__ Wb,
                                            const float* __restrict__ bias, short* __restrict__ Rb,
                                            float* __restrict__ stats, int slot_out){
  GEMM_PROLOGUE();
  const short* Asrc = Y + ((size_t)(b*NL)+l0)*ND;
  const short* Bsrc = Wb + (size_t)e0*ND;
  for(int c=0;c<2;c++){
    __syncthreads();
    stage_rows_bf16(As, Asrc, tid, c);
    stage_rows_bf16(Bs, Bsrc, tid, c);
    __syncthreads();
    mfma_core(As, Bs, wm, wn, lq, gg, acc);
  }
  float s=0.f, ss=0.f;
  #pragma unroll
  for(int n=0;n<2;n++){
    int e = e0 + wn*32 + n*16 + lq;
    float bv = bias[e];
    #pragma unroll
    for(int m=0;m<2;m++){
      #pragma unroll
      for(int r=0;r<4;r++){
        int l = l0 + wm*32 + m*16 + gg*4 + r;
        size_t ix = (size_t)(b*NL+l)*ND + e;
        float v = fmaxf(acc[m][n][r] + bv, 0.f);
        float rr = b2f(Rb[ix]) + v;
        short rs = bf16s(rr);
        Rb[ix] = rs;
        float r2 = b2f(rs);
        s += r2; ss += r2*r2;
      }
    }
  }
  stats_reduce(s, ss, stats, slot_out, b, blk & 7);
}

// ---- fused QKV: LN(Rb) x Wcat -> Qb/Kb bf16 [b][h][l][dk], Vb bf16 V^T [b][h][v][l] ----
__global__ __launch_bounds__(256) void k_qkvf(const short* __restrict__ Rb, const short* __restrict__ gT,
                                              const short* __restrict__ bT, const float* __restrict__ stats,
                                              const short* __restrict__ Wcat, short* __restrict__ Qb,
                                              short* __restrict__ Kb, short* __restrict__ Vb){
  int blk = blockIdx.x;                 // b*192 + et*16 + lt
  int lt = blk & 15;
  int tmp = blk >> 4;
  int et = tmp % 12, b = tmp / 12;
  int l0 = lt*64, e0g = et*64;
  int seg = et >> 2;                    // 0=Q,1=K,2=V
  int tid = threadIdx.x;
  int w = tid>>6, lane = tid&63, lq = lane&15, gg = lane>>4;
  int wm = w&1, wn = w>>1;
  __shared__ short As[8192], Bs[8192];
  f32x4 acc[2][2];
  acc[0][0]=acc[0][1]=acc[1][0]=acc[1][1] = (f32x4){0.f,0.f,0.f,0.f};
  float mean, rstd; ln_ab(stats, 4, b, mean, rstd);
  const short* Asrc = Rb + ((size_t)(b*NL)+l0)*ND;
  const short* gs = gT + (size_t)l0*ND;
  const short* bs = bT + (size_t)l0*ND;
  const short* Bsrc = Wcat + (size_t)e0g*ND;
  for(int c=0;c<2;c++){
    __syncthreads();
    stage_act_lnb(As, Asrc, gs, bs, mean, rstd, tid, c);
    stage_rows_bf16(Bs, Bsrc, tid, c);
    __syncthreads();
    mfma_core(As, Bs, wm, wn, lq, gg, acc);
  }
  #pragma unroll
  for(int n=0;n<2;n++){
    int eo = (et&3)*64 + wn*32 + n*16 + lq;   // 0..255 within segment
    int h = eo>>5, dk = eo&31;
    if(seg < 2){
      short* outp = (seg==0) ? Qb : Kb;
      #pragma unroll
      for(int m=0;m<2;m++){
        #pragma unroll
        for(int r=0;r<4;r++){
          int l = l0 + wm*32 + m*16 + gg*4 + r;
          outp[((size_t)(b*NHH+h)*NL + l)*NDK + dk] = bf16s(acc[m][n][r]);
        }
      }
    } else {
      #pragma unroll
      for(int m=0;m<2;m++){
        int lb = l0 + wm*32 + m*16 + gg*4;
        bf16x4 pk;
        #pragma unroll
        for(int r=0;r<4;r++) pk[r] = bf16s(acc[m][n][r]);
        *(bf16x4*)(Vb + ((size_t)(b*NHH+h)*NDK + dk)*NL + lb) = pk;
      }
    }
  }
}

// ---------------- MFMA flash attention; LDS-staged K/V; XCD-swizzled; swizzled Vs ----------------
__global__ __launch_bounds__(256) void k_attn(const short* __restrict__ Qb, const short* __restrict__ Kb,
                                              const short* __restrict__ Vt, const int* __restrict__ mask,
                                              short* __restrict__ heads){
  int blk = blockIdx.x;
  // 16 qblks of one (b,h) are 128 apart -> same XCD -> K/V stays in that L2
  int qblk = blk >> 7, bh = blk & 127;
  int b = bh >> 3, h = bh & 7;
  int tid = threadIdx.x;
  int w = tid >> 6, lane = tid & 63;
  int lq = lane & 15, gg = lane >> 4;

  __shared__ short Ks[64][40];      // padded: 2-way alias only (free)
  __shared__ short Vs[32*64];       // flat [32 rows][128B], XOR-swizzled: byte ^= (row&7)<<4
  __shared__ short Ps[4][16][40];   // per-wave P scratch, 80B rows (16B-aligned b128 reads)
  __shared__ float msh[64];

  int qrow = qblk*64 + w*16 + lq;
  bf16x8 qf = *(const bf16x8*)(Qb + ((size_t)bh*NL + qrow)*NDK + gg*8);

  bf16x8 ones;
  #pragma unroll
  for(int j=0;j<8;j++) ones[j] = (short)0x3F80;   // 1.0bf16

  f32x4 zero = {0.f,0.f,0.f,0.f};
  f32x4 o0 = zero, o1 = zero, o2 = zero;          // o2 = row denominators
  const float scale = 0.17677669529663687f;       // 1/sqrt(32)

  for(int t0=0; t0<NL; t0+=64){
    __syncthreads();
    {
      int key = tid >> 2, c = tid & 3;
      *(bf16x8*)(&Ks[key][c*8]) = *(const bf16x8*)(Kb + ((size_t)bh*NL + t0 + key)*NDK + c*8);
      int v = tid >> 3, ch = tid & 7;
      // swizzled write: conflict-free (banks 8v%32 + 4*(ch^(v&7)) distinct per phase)
      *(bf16x8*)((char*)Vs + v*128 + ((ch*16) ^ ((v&7)<<4))) =
          *(const bf16x8*)(Vt + ((size_t)bh*NDK + v)*NL + t0 + ch*8);
      if(tid < 64) msh[tid] = ((float)mask[b*NL + t0 + tid] - 1.f) * 1e30f;   // additive bias
    }
    __syncthreads();
    #pragma unroll
    for(int sub=0; sub<2; sub++){
      bf16x8 a0 = *(const bf16x8*)(&Ks[sub*32 + lq][gg*8]);
      bf16x8 a1 = *(const bf16x8*)(&Ks[sub*32 + 16 + lq][gg*8]);
      f32x4 c0 = __builtin_amdgcn_mfma_f32_16x16x32_bf16(a0, qf, zero, 0, 0, 0);
      f32x4 c1 = __builtin_amdgcn_mfma_f32_16x16x32_bf16(a1, qf, zero, 0, 0, 0);
      bf16x4 p0, p1;
      #pragma unroll
      for(int r=0;r<4;r++){
        float pv0 = __expf(__builtin_fmaf(c0[r], scale, msh[sub*32 + gg*4 + r]));
        p0[r] = bf16s(pv0);
        float pv1 = __expf(__builtin_fmaf(c1[r], scale, msh[sub*32 + 16 + gg*4 + r]));
        p1[r] = bf16s(pv1);
      }
      *(bf16x4*)(&Ps[w][lq][gg*4])      = p0;
      *(bf16x4*)(&Ps[w][lq][16 + gg*4]) = p1;
      bf16x8 pf = *(const bf16x8*)(&Ps[w][lq][gg*8]);
      int cc = sub*4 + gg;              // 16B chunk index within a V row
      bf16x8 b0 = *(const bf16x8*)((const char*)Vs + lq*128      + ((cc*16) ^ ((lq&7)<<4)));
      bf16x8 b1 = *(const bf16x8*)((const char*)Vs + (16+lq)*128 + ((cc*16) ^ (((16+lq)&7)<<4)));
      o0 = __builtin_amdgcn_mfma_f32_16x16x32_bf16(pf, b0, o0, 0, 0, 0);
      o1 = __builtin_amdgcn_mfma_f32_16x16x32_bf16(pf, b1, o1, 0, 0, 0);
      o2 = __builtin_amdgcn_mfma_f32_16x16x32_bf16(pf, ones, o2, 0, 0, 0);
    }
  }
  #pragma unroll
  for(int r=0;r<4;r++){
    int ql = gg*4 + r;
    int qg = qblk*64 + w*16 + ql;
    float mq = (float)mask[b*NL + qg];
    float sc = mq / o2[r];
    short* op = heads + ((size_t)(b*NL + qg))*(NHH*NDK) + h*NDK;
    op[lq]      = bf16s(o0[r]*sc);
    op[16 + lq] = bf16s(o1[r]*sc);
  }
}

// ---- wo: heads(bf16) x Wo^T -> Rb += (in place), stats slot 5 ----
__global__ __launch_bounds__(256) void k_wo(const short* __restrict__ H, const short* __restrict__ Wb,
                                            short* __restrict__ Rb, float* __restrict__ stats){
  GEMM_PROLOGUE();
  const short* Asrc = H + ((size_t)(b*NL)+l0)*ND;
  const short* Bsrc = Wb + (size_t)e0*ND;
  for(int c=0;c<2;c++){
    __syncthreads();
    stage_rows_bf16(As, Asrc, tid, c);
    stage_rows_bf16(Bs, Bsrc, tid, c);
    __syncthreads();
    mfma_core(As, Bs, wm, wn, lq, gg, acc);
  }
  float s=0.f, ss=0.f;
  #pragma unroll
  for(int n=0;n<2;n++){
    int e = e0 + wn*32 + n*16 + lq;
    #pragma unroll
    for(int m=0;m<2;m++){
      #pragma unroll
      for(int r=0;r<4;r++){
        int l = l0 + wm*32 + m*16 + gg*4 + r;
        size_t ix = (size_t)(b*NL+l)*ND + e;
        float rr = b2f(Rb[ix]) + acc[m][n][r];
        short rs = bf16s(rr);
        Rb[ix] = rs;
        float r2 = b2f(rs);
        s += r2; ss += r2*r2;
      }
    }
  }
  stats_reduce(s, ss, stats, 5, b, blk & 7);
}

// ---- fc: LN5(Rb) x fc_w -> relu+bias, + Rb -> d_out [b][e][l] fp32 ----
__global__ __launch_bounds__(256) void k_fc(const short* __restrict__ Rb, const short* __restrict__ gT,
                                            const short* __restrict__ bT, const float* __restrict__ stats,
                                            const short* __restrict__ Wb, const float* __restrict__ bias,
                                            float* __restrict__ out){
  GEMM_PROLOGUE();
  float mean, rstd; ln_ab(stats, 5, b, mean, rstd);
  const short* Asrc = Rb + ((size_t)(b*NL)+l0)*ND;
  const short* gs = gT + (size_t)l0*ND;
  const short* bs = bT + (size_t)l0*ND;
  const short* Bsrc = Wb + (size_t)e0*ND;
  for(int c=0;c<2;c++){
    __syncthreads();
    stage_act_lnb(As, Asrc, gs, bs, mean, rstd, tid, c);
    stage_rows_bf16(Bs, Bsrc, tid, c);
    __syncthreads();
    mfma_core(As, Bs, wm, wn, lq, gg, acc);
  }
  #pragma unroll
  for(int n=0;n<2;n++){
    int e = e0 + wn*32 + n*16 + lq;
    float bv = bias[e];
    #pragma unroll
    for(int m=0;m<2;m++){
      int lb = l0 + wm*32 + m*16 + gg*4;
      f32x4 ov;
      #pragma unroll
      for(int r=0;r<4;r++){
        float v = fmaxf(acc[m][n][r] + bv, 0.f);
        ov[r] = v + b2f(Rb[(size_t)(b*NL+lb+r)*ND + e]);
      }
      *(f32x4*)(out + (size_t)(b*ND+e)*NL + lb) = ov;
    }
  }
}

extern "C" void kernel_launch(void* const* d_in, const int* in_sizes, int n_in,
                              void* d_out, int out_size, void* d_ws, size_t ws_size,
                              hipStream_t stream){
  const float* x    = (const float*)d_in[0];
  const int*   mask = (const int*)d_in[1];
  const float* dw_w = (const float*)d_in[2];
  const float* dw_b = (const float*)d_in[3];
  const float* pw_w = (const float*)d_in[4];
  const float* pw_b = (const float*)d_in[5];
  const float* ln_g = (const float*)d_in[6];
  const float* ln_b = (const float*)d_in[7];
  const float* Wq   = (const float*)d_in[8];
  const float* Wk   = (const float*)d_in[9];
  const float* Wv   = (const float*)d_in[10];
  const float* Wo   = (const float*)d_in[11];
  const float* fc_w = (const float*)d_in[12];
  const float* fc_b = (const float*)d_in[13];

  float* ws     = (float*)d_ws;
  float* stats  = ws;                          // 98304 floats
  float* postab = ws + 98304;                  // 262144 floats
  short* Rb     = (short*)(ws + 360448);       // 4194304 bf16 [b][l][d]
  short* Yb     = (short*)(ws + 2457600);      // 4194304 bf16 (dwconv out)
  short* Hb     = (short*)(ws + 4554752);      // heads
  short* Qb     = (short*)(ws + 6651904);
  short* Kb     = (short*)(ws + 8749056);
  short* Vb     = (short*)(ws + 10846208);
  short* gT     = (short*)(ws + 12943360);     // 6*262144 bf16
  short* bT     = (short*)(ws + 13729792);
  short* Wpwb   = (short*)(ws + 14516224);     // 262144 bf16
  short* Wfcb   = (short*)(ws + 14647296);     // 65536
  short* Wob    = (short*)(ws + 14680064);     // 65536
  short* Wcat   = (short*)(ws + 14712832);     // 196608 bf16

  hipMemsetAsync(stats, 0, 98304*sizeof(float), stream);
  k_prep<<<1600,256,0,stream>>>(pw_w, fc_w, Wo, Wq, Wk, Wv, ln_g, ln_b,
                                Wpwb, Wfcb, Wob, Wcat, gT, bT, postab);
  k_posadd<<<1024,256,0,stream>>>(x, postab, Rb, stats);
  for(int i=0;i<NCONV;i++){
    k_dwconvT<<<1024,256,0,stream>>>(Rb, gT + (size_t)i*NPB, bT + (size_t)i*NPB,
                                     dw_w + i*ND*NKW, dw_b + i*ND, stats, Yb, i);
    k_pw<<<1024,256,0,stream>>>(Yb, Wpwb + (size_t)i*65536, pw_b + i*ND, Rb, stats, i+1);
  }
  k_qkvf<<<3072,256,0,stream>>>(Rb, gT + (size_t)4*NPB, bT + (size_t)4*NPB, stats, Wcat, Qb, Kb, Vb);
  k_attn<<<2048,256,0,stream>>>(Qb, Kb, Vb, mask, Hb);
  k_wo<<<1024,256,0,stream>>>(Hb, Wob, Rb, stats);
  k_fc<<<1024,256,0,stream>>>(Rb, gT + (size_t)5*NPB, bT + (size_t)5*NPB, stats, Wfcb, fc_b, (float*)d_out);
}

// Round 9
// 288.305 us; speedup vs baseline: 1.3248x; 1.0390x over previous
//
#include <hip/hip_runtime.h>
#include <hip/hip_bf16.h>

#define NB 16
#define ND 256
#define NL 1024
#define NHH 8
#define NDK 32
#define NKW 7
#define NCONV 4
#define NPB (ND*NL)

constexpr float LN_EPS = 1e-5f;

typedef __attribute__((ext_vector_type(4))) float f32x4;
typedef __attribute__((ext_vector_type(4))) short bf16x4;
typedef __attribute__((ext_vector_type(8))) short bf16x8;

__device__ __forceinline__ short bf16s(float f){   // RNE via HW conversion (pairs into cvt_pk)
  return (short)__builtin_bit_cast(unsigned short, __float2bfloat16(f));
}
__device__ __forceinline__ float b2f(short s){
  return __builtin_bit_cast(float, ((unsigned)(unsigned short)s) << 16);
}

// ---------------- LN stats: 8 bins x 128B apart per (slot,b) ----------------
__device__ __forceinline__ void ln_ab(const float* st, int slot, int b, float& mean, float& rstd){
  float s = 0.f, ss = 0.f;
  #pragma unroll
  for(int bin=0;bin<8;bin++){
    const float* p = st + ((size_t)((slot*NB+b)*8+bin))*32;
    s += p[0]; ss += p[1];
  }
  mean = s * (1.0f/NPB);
  float var = ss * (1.0f/NPB) - mean*mean;
  rstd = rsqrtf(var + LN_EPS);
}

__device__ __forceinline__ void stats_reduce(float s, float ss, float* stats, int slot, int b, int bin){
  __shared__ float red[8];
  #pragma unroll
  for(int o=32;o>0;o>>=1){ s += __shfl_down(s,o); ss += __shfl_down(ss,o); }
  int lane = threadIdx.x & 63, w = threadIdx.x >> 6;
  if(lane==0){ red[w*2]=s; red[w*2+1]=ss; }
  __syncthreads();
  if(threadIdx.x==0){
    float* p = stats + ((size_t)((slot*NB+b)*8+bin))*32;
    atomicAdd(&p[0], red[0]+red[2]+red[4]+red[6]);
    atomicAdd(&p[1], red[1]+red[3]+red[5]+red[7]);
  }
}

// ---------------- one-shot prep ----------------
__global__ __launch_bounds__(256) void k_prep(const float* __restrict__ pw_w, const float* __restrict__ fc_w,
    const float* __restrict__ Wo, const float* __restrict__ Wq, const float* __restrict__ Wk,
    const float* __restrict__ Wv, const float* __restrict__ g, const float* __restrict__ btab,
    short* __restrict__ Wpwb, short* __restrict__ Wfcb, short* __restrict__ Wob, short* __restrict__ Wcat,
    short* __restrict__ gT, short* __restrict__ bT, float* __restrict__ postab){
  __shared__ float T[64][65];
  int blk = blockIdx.x, tid = threadIdx.x;
  if(blk < 256){                     // pw_w -> bf16
    int idx = blk*1024 + tid*4;
    f32x4 v = *(const f32x4*)(pw_w + idx);
    bf16x4 o;
    #pragma unroll
    for(int j=0;j<4;j++) o[j] = bf16s(v[j]);
    *(bf16x4*)(Wpwb + idx) = o;
  } else if(blk < 320){              // fc_w -> bf16
    int idx = (blk-256)*1024 + tid*4;
    f32x4 v = *(const f32x4*)(fc_w + idx);
    bf16x4 o;
    #pragma unroll
    for(int j=0;j<4;j++) o[j] = bf16s(v[j]);
    *(bf16x4*)(Wfcb + idx) = o;
  } else if(blk < 384){              // Wo[d][e] -> bf16 [e][d]
    int idx = (blk-320)*1024 + tid*4;
    int e = idx >> 8;
    bf16x4 o;
    #pragma unroll
    for(int j=0;j<4;j++){ int d = (idx+j)&255; o[j] = bf16s(Wo[d*ND + e]); }
    *(bf16x4*)(Wob + idx) = o;
  } else if(blk < 576){              // Wq/Wk/Wv -> Wcat[(seg*256+h*32+k)][d]
    int idx = (blk-384)*1024 + tid*4;
    int og = idx >> 8, d = idx & 255;
    int seg = og >> 8, o = og & 255, h = o >> 5, k = o & 31;
    const float* W = (seg==0) ? Wq : ((seg==1) ? Wk : Wv);
    bf16x4 ov;
    #pragma unroll
    for(int j=0;j<4;j++) ov[j] = bf16s(W[((size_t)(h*ND + d + j))*NDK + k]);
    *(bf16x4*)(Wcat + idx) = ov;
  } else if(blk < 832){              // pos table [d][l]
    int d = blk - 576;
    int l = tid*4;
    const float LN1E4_OVER_D = 9.210340371976184f / (float)ND;
    float freq, phase;
    if((d & 1) == 0){ freq =  __expf(-(float)d*LN1E4_OVER_D);      phase = 0.f; }
    else            { freq = -__expf((1.f-(float)d)*LN1E4_OVER_D); phase = 1.5707963267948966f; }
    f32x4 o;
    #pragma unroll
    for(int j=0;j<4;j++) o[j] = sinf((float)(l+j)*freq + phase);
    *(f32x4*)(postab + ((size_t)d<<10) + l) = o;
  } else {                           // ln_g/ln_b [slot][d][l] -> bf16 [slot][l][d]
    int blk2 = blk - 832;
    int which = blk2 >> 6;
    int tile = blk2 & 63;
    int d0 = (tile & 3) << 6, l0 = (tile >> 2) << 6;
    const float* src = (which < 6) ? (g + (size_t)which*NPB) : (btab + (size_t)(which-6)*NPB);
    short* dst = (which < 6) ? (gT + (size_t)which*NPB) : (bT + (size_t)(which-6)*NPB);
    for(int i=tid;i<1024;i+=256){
      int dd = i>>4, l4 = i&15;
      f32x4 v = *(const f32x4*)(src + (size_t)(d0+dd)*NL + l0 + l4*4);
      #pragma unroll
      for(int j=0;j<4;j++) T[dd][l4*4+j] = v[j];
    }
    __syncthreads();
    for(int i=tid;i<1024;i+=256){
      int ll = i>>4, d4 = i&15;
      bf16x4 o;
      #pragma unroll
      for(int j=0;j<4;j++) o[j] = bf16s(T[d4*4+j][ll]);
      *(bf16x4*)(dst + (size_t)(l0+ll)*ND + d0 + d4*4) = o;
    }
  }
}

// ---------------- x + pos -> Rb [b][l][d] bf16, stats slot 0 ----------------
__global__ __launch_bounds__(256) void k_posadd(const float* __restrict__ x, const float* __restrict__ postab,
                                                short* __restrict__ Rb, float* __restrict__ stats){
  int blk = blockIdx.x;
  int lt = blk & 15, dt = (blk>>4)&3, b = blk>>6;
  int l0 = lt*64, d0 = dt*64;
  __shared__ float T[64][65];
  int tid = threadIdx.x;
  for(int i=tid;i<1024;i+=256){
    int dd = i>>4, l4 = i&15;
    int d = d0+dd;
    f32x4 xv = *(const f32x4*)(x + ((size_t)(b*ND+d)<<10) + l0 + l4*4);
    f32x4 pv = *(const f32x4*)(postab + ((size_t)d<<10) + l0 + l4*4);
    #pragma unroll
    for(int j=0;j<4;j++) T[dd][l4*4+j] = xv[j] + pv[j];
  }
  __syncthreads();
  float s=0.f, ss=0.f;
  for(int i=tid;i<1024;i+=256){
    int ll = i>>4, d4 = i&15;
    bf16x4 o;
    #pragma unroll
    for(int j=0;j<4;j++){
      short rs = bf16s(T[d4*4+j][ll]);
      o[j] = rs;
      float rv = b2f(rs);
      s += rv; ss += rv*rv;
    }
    *(bf16x4*)(Rb + ((size_t)(b*NL+l0+ll)<<8) + d0 + d4*4) = o;
  }
  stats_reduce(s, ss, stats, 0, b, blk & 7);
}

// ---------------- depthwise conv, vectorized 4d x 4l per thread, bf16 R ----------------
__global__ __launch_bounds__(256) void k_dwconvT(const short* __restrict__ Rb, const short* __restrict__ gT,
                                                 const short* __restrict__ bT, const float* __restrict__ w7,
                                                 const float* __restrict__ db, const float* __restrict__ stats,
                                                 short* __restrict__ Y, int slot){
  int blk = blockIdx.x;               // b*64 + lblk
  int lblk = blk & 63, b = blk >> 6;
  int tid = threadIdx.x;
  __shared__ float wLds[NKW][ND];
  __shared__ float dbLds[ND];
  for(int i=tid;i<ND*NKW;i+=256){ int d=i/NKW, q=i-d*NKW; wLds[q][d] = w7[i]; }
  dbLds[tid] = db[tid];
  float mean, rstd; ln_ab(stats, slot, b, mean, rstd);
  float mr = mean*rstd;
  __syncthreads();
  int d0 = (tid & 63)*4;
  int l0 = lblk*16 + (tid >> 6)*4;
  f32x4 ln[10];
  #pragma unroll
  for(int i=0;i<10;i++){
    int lp = l0 - 3 + i;
    if(lp >= 0 && lp < NL){
      bf16x4 v = *(const bf16x4*)(Rb + ((size_t)(b*NL+lp)<<8) + d0);
      bf16x4 gv = *(const bf16x4*)(gT + ((size_t)lp<<8) + d0);
      bf16x4 bv = *(const bf16x4*)(bT + ((size_t)lp<<8) + d0);
      f32x4 t;
      #pragma unroll
      for(int j=0;j<4;j++) t[j] = (b2f(v[j])*rstd - mr)*b2f(gv[j]) + b2f(bv[j]);
      ln[i] = t;
    } else ln[i] = (f32x4){0.f,0.f,0.f,0.f};
  }
  f32x4 dbv = *(const f32x4*)(&dbLds[d0]);
  #pragma unroll
  for(int jl=0;jl<4;jl++){
    f32x4 acc = dbv;
    #pragma unroll
    for(int q=0;q<NKW;q++){
      f32x4 wq = *(const f32x4*)(&wLds[q][d0]);
      #pragma unroll
      for(int j=0;j<4;j++) acc[j] += ln[jl+q][j]*wq[j];
    }
    bf16x4 o;
    #pragma unroll
    for(int j=0;j<4;j++) o[j] = bf16s(acc[j]);
    *(bf16x4*)(Y + ((size_t)(b*NL + l0 + jl)<<8) + d0) = o;
  }
}

// ---------------- shared MFMA GEMM pieces ----------------
// T14 async-STAGE: load to regs early, write to LDS late.
__device__ __forceinline__ void load_rows_regs(bf16x8 r[4], const short* src, int tid, int c){
  #pragma unroll
  for(int it=0;it<4;it++){
    int i = tid + it*256;
    int rr = i>>4, kk = i&15;
    r[it] = *(const bf16x8*)(src + (size_t)rr*ND + c*128 + kk*8);
  }
}
__device__ __forceinline__ void write_rows_lds(short* dst, const bf16x8 r[4], int tid){
  #pragma unroll
  for(int it=0;it<4;it++){
    int i = tid + it*256;
    int rr = i>>4, kk = i&15;
    *(bf16x8*)((char*)dst + rr*256 + ((kk*16) ^ ((rr&7)<<4))) = r[it];
  }
}
// apply LN affine at write time (raw residual regs already loaded)
__device__ __forceinline__ void write_act_lds(short* dst, const bf16x8 rv[4], const short* g, const short* bt,
                                              float mean, float rstd, int tid, int c){
  float mr = mean*rstd;
  #pragma unroll
  for(int it=0;it<4;it++){
    int i = tid + it*256;
    int ll = i>>4, kk = i&15;
    size_t off = (size_t)ll*ND + c*128 + kk*8;
    bf16x8 gv = *(const bf16x8*)(g + off);
    bf16x8 bv = *(const bf16x8*)(bt + off);
    bf16x8 o;
    #pragma unroll
    for(int j=0;j<8;j++) o[j] = bf16s((b2f(rv[it][j])*rstd - mr)*b2f(gv[j]) + b2f(bv[j]));
    *(bf16x8*)((char*)dst + ll*256 + ((kk*16) ^ ((ll&7)<<4))) = o;
  }
}
// legacy one-shot staging (used by k_qkvf, unchanged this round)
__device__ __forceinline__ void stage_rows_bf16(short* dst, const short* src, int tid, int c){
  for(int i=tid;i<1024;i+=256){
    int rr = i>>4, kk = i&15;
    bf16x8 w = *(const bf16x8*)(src + (size_t)rr*ND + c*128 + kk*8);
    *(bf16x8*)((char*)dst + rr*256 + ((kk*16) ^ ((rr&7)<<4))) = w;
  }
}
__device__ __forceinline__ void stage_act_lnb(short* dst, const short* src, const short* g, const short* bt,
                                              float mean, float rstd, int tid, int c){
  float mr = mean*rstd;
  for(int i=tid;i<1024;i+=256){
    int ll = i>>4, kk = i&15;
    size_t off = (size_t)ll*ND + c*128 + kk*8;
    bf16x8 v = *(const bf16x8*)(src + off);
    bf16x8 gv = *(const bf16x8*)(g + off);
    bf16x8 bv = *(const bf16x8*)(bt + off);
    bf16x8 o;
    #pragma unroll
    for(int j=0;j<8;j++) o[j] = bf16s((b2f(v[j])*rstd - mr)*b2f(gv[j]) + b2f(bv[j]));
    *(bf16x8*)((char*)dst + ll*256 + ((kk*16) ^ ((ll&7)<<4))) = o;
  }
}
__device__ __forceinline__ void mfma_core(const short* As, const short* Bs, int wm, int wn,
                                          int lq, int gg, f32x4 acc[2][2]){
  #pragma unroll
  for(int t=0;t<4;t++){
    bf16x8 a[2], bb[2];
    #pragma unroll
    for(int m=0;m<2;m++){
      int row = wm*32 + m*16 + lq;
      a[m] = *(const bf16x8*)((const char*)As + row*256 + ((t*64 + gg*16) ^ ((row&7)<<4)));
    }
    #pragma unroll
    for(int n=0;n<2;n++){
      int row = wn*32 + n*16 + lq;
      bb[n] = *(const bf16x8*)((const char*)Bs + row*256 + ((t*64 + gg*16) ^ ((row&7)<<4)));
    }
    #pragma unroll
    for(int m=0;m<2;m++)
      #pragma unroll
      for(int n=0;n<2;n++)
        acc[m][n] = __builtin_amdgcn_mfma_f32_16x16x32_bf16(a[m], bb[n], acc[m][n], 0,0,0);
  }
}

#define GEMM_PROLOGUE() \
  int blk = blockIdx.x; \
  int lt = blk & 15, et = (blk>>4)&3, b = blk>>6; \
  int l0 = lt*64, e0 = et*64; \
  int tid = threadIdx.x; \
  int w = tid>>6, lane = tid&63, lq = lane&15, gg = lane>>4; \
  int wm = w&1, wn = w>>1; \
  __shared__ short As[8192], Bs[8192]; \
  f32x4 acc[2][2]; \
  acc[0][0]=acc[0][1]=acc[1][0]=acc[1][1] = (f32x4){0.f,0.f,0.f,0.f};

// ---- pw: Yb(bf16) x W -> relu+bias, Rb += , stats  (T14 pipelined) ----
__global__ __launch_bounds__(256) void k_pw(const short* __restrict__ Y, const short* __restrict__ Wb,
                                            const float* __restrict__ bias, short* __restrict__ Rb,
                                            float* __restrict__ stats, int slot_out){
  GEMM_PROLOGUE();
  const short* Asrc = Y + ((size_t)(b*NL)+l0)*ND;
  const short* Bsrc = Wb + (size_t)e0*ND;
  bf16x8 ra[4], rbw[4];
  load_rows_regs(ra, Asrc, tid, 0);
  load_rows_regs(rbw, Bsrc, tid, 0);
  #pragma unroll
  for(int c=0;c<2;c++){
    __syncthreads();
    write_rows_lds(As, ra, tid);
    write_rows_lds(Bs, rbw, tid);
    if(c==0){ load_rows_regs(ra, Asrc, tid, 1); load_rows_regs(rbw, Bsrc, tid, 1); }
    __syncthreads();
    mfma_core(As, Bs, wm, wn, lq, gg, acc);
  }
  float s=0.f, ss=0.f;
  #pragma unroll
  for(int n=0;n<2;n++){
    int e = e0 + wn*32 + n*16 + lq;
    float bv = bias[e];
    #pragma unroll
    for(int m=0;m<2;m++){
      #pragma unroll
      for(int r=0;r<4;r++){
        int l = l0 + wm*32 + m*16 + gg*4 + r;
        size_t ix = (size_t)(b*NL+l)*ND + e;
        float v = fmaxf(acc[m][n][r] + bv, 0.f);
        float rr = b2f(Rb[ix]) + v;
        short rs = bf16s(rr);
        Rb[ix] = rs;
        float r2 = b2f(rs);
        s += r2; ss += r2*r2;
      }
    }
  }
  stats_reduce(s, ss, stats, slot_out, b, blk & 7);
}

// ---- fused QKV: LN(Rb) x Wcat -> Qb/Kb bf16 [b][h][l][dk], Vb bf16 V^T [b][h][v][l] ----
__global__ __launch_bounds__(256) void k_qkvf(const short* __restrict__ Rb, const short* __restrict__ gT,
                                              const short* __restrict__ bT, const float* __restrict__ stats,
                                              const short* __restrict__ Wcat, short* __restrict__ Qb,
                                              short* __restrict__ Kb, short* __restrict__ Vb){
  int blk = blockIdx.x;                 // b*192 + et*16 + lt
  int lt = blk & 15;
  int tmp = blk >> 4;
  int et = tmp % 12, b = tmp / 12;
  int l0 = lt*64, e0g = et*64;
  int seg = et >> 2;                    // 0=Q,1=K,2=V
  int tid = threadIdx.x;
  int w = tid>>6, lane = tid&63, lq = lane&15, gg = lane>>4;
  int wm = w&1, wn = w>>1;
  __shared__ short As[8192], Bs[8192];
  f32x4 acc[2][2];
  acc[0][0]=acc[0][1]=acc[1][0]=acc[1][1] = (f32x4){0.f,0.f,0.f,0.f};
  float mean, rstd; ln_ab(stats, 4, b, mean, rstd);
  const short* Asrc = Rb + ((size_t)(b*NL)+l0)*ND;
  const short* gs = gT + (size_t)l0*ND;
  const short* bs = bT + (size_t)l0*ND;
  const short* Bsrc = Wcat + (size_t)e0g*ND;
  for(int c=0;c<2;c++){
    __syncthreads();
    stage_act_lnb(As, Asrc, gs, bs, mean, rstd, tid, c);
    stage_rows_bf16(Bs, Bsrc, tid, c);
    __syncthreads();
    mfma_core(As, Bs, wm, wn, lq, gg, acc);
  }
  #pragma unroll
  for(int n=0;n<2;n++){
    int eo = (et&3)*64 + wn*32 + n*16 + lq;   // 0..255 within segment
    int h = eo>>5, dk = eo&31;
    if(seg < 2){
      short* outp = (seg==0) ? Qb : Kb;
      #pragma unroll
      for(int m=0;m<2;m++){
        #pragma unroll
        for(int r=0;r<4;r++){
          int l = l0 + wm*32 + m*16 + gg*4 + r;
          outp[((size_t)(b*NHH+h)*NL + l)*NDK + dk] = bf16s(acc[m][n][r]);
        }
      }
    } else {
      #pragma unroll
      for(int m=0;m<2;m++){
        int lb = l0 + wm*32 + m*16 + gg*4;
        bf16x4 pk;
        #pragma unroll
        for(int r=0;r<4;r++) pk[r] = bf16s(acc[m][n][r]);
        *(bf16x4*)(Vb + ((size_t)(b*NHH+h)*NDK + dk)*NL + lb) = pk;
      }
    }
  }
}

// ---------------- MFMA flash attention; LDS-staged K/V; XCD-swizzled; T14 async-STAGE ----------------
__global__ __launch_bounds__(256) void k_attn(const short* __restrict__ Qb, const short* __restrict__ Kb,
                                              const short* __restrict__ Vt, const int* __restrict__ mask,
                                              short* __restrict__ heads){
  int blk = blockIdx.x;
  // 16 qblks of one (b,h) are 128 apart -> same XCD -> K/V stays in that L2
  int qblk = blk >> 7, bh = blk & 127;
  int b = bh >> 3, h = bh & 7;
  int tid = threadIdx.x;
  int w = tid >> 6, lane = tid & 63;
  int lq = lane & 15, gg = lane >> 4;

  __shared__ short Ks[64][40];      // padded: 2-way alias only (free)
  __shared__ short Vs[32*64];       // flat [32 rows][128B], XOR-swizzled: byte ^= (row&7)<<4
  __shared__ short Ps[4][16][40];   // per-wave P scratch, 80B rows (16B-aligned b128 reads)
  __shared__ float msh[64];

  int qrow = qblk*64 + w*16 + lq;
  bf16x8 qf = *(const bf16x8*)(Qb + ((size_t)bh*NL + qrow)*NDK + gg*8);

  bf16x8 ones;
  #pragma unroll
  for(int j=0;j<8;j++) ones[j] = (short)0x3F80;   // 1.0bf16

  f32x4 zero = {0.f,0.f,0.f,0.f};
  f32x4 o0 = zero, o1 = zero, o2 = zero;          // o2 = row denominators
  const float scale = 0.17677669529663687f;       // 1/sqrt(32)

  const short* Kst = Kb + (size_t)bh*NL*NDK;
  const short* Vst = Vt + (size_t)bh*NDK*NL;
  int skey = tid >> 2, sc = tid & 3;     // K staging: row skey, 16B chunk sc
  int sv = tid >> 3, sch = tid & 7;      // V staging: row sv, chunk sch

  // T14 prologue: tile-0 loads into regs
  bf16x8 kreg = *(const bf16x8*)(Kst + (size_t)skey*NDK + sc*8);
  bf16x8 vreg = *(const bf16x8*)(Vst + (size_t)sv*NL + sch*8);
  float mreg = 0.f;
  if(tid < 64) mreg = ((float)mask[b*NL + tid] - 1.f) * 1e30f;

  for(int t0=0; t0<NL; t0+=64){
    __syncthreads();                     // previous tile's compute done reading LDS
    *(bf16x8*)(&Ks[skey][sc*8]) = kreg;
    *(bf16x8*)((char*)Vs + sv*128 + ((sch*16) ^ ((sv&7)<<4))) = vreg;
    if(tid < 64) msh[tid] = mreg;
    if(t0 + 64 < NL){                    // issue next tile's loads; latency hides under compute
      kreg = *(const bf16x8*)(Kst + (size_t)(t0 + 64 + skey)*NDK + sc*8);
      vreg = *(const bf16x8*)(Vst + (size_t)sv*NL + t0 + 64 + sch*8);
      if(tid < 64) mreg = ((float)mask[b*NL + t0 + 64 + tid] - 1.f) * 1e30f;
    }
    __syncthreads();                     // staged tile visible
    #pragma unroll
    for(int sub=0; sub<2; sub++){
      bf16x8 a0 = *(const bf16x8*)(&Ks[sub*32 + lq][gg*8]);
      bf16x8 a1 = *(const bf16x8*)(&Ks[sub*32 + 16 + lq][gg*8]);
      f32x4 c0 = __builtin_amdgcn_mfma_f32_16x16x32_bf16(a0, qf, zero, 0, 0, 0);
      f32x4 c1 = __builtin_amdgcn_mfma_f32_16x16x32_bf16(a1, qf, zero, 0, 0, 0);
      bf16x4 p0, p1;
      #pragma unroll
      for(int r=0;r<4;r++){
        float pv0 = __expf(__builtin_fmaf(c0[r], scale, msh[sub*32 + gg*4 + r]));
        p0[r] = bf16s(pv0);
        float pv1 = __expf(__builtin_fmaf(c1[r], scale, msh[sub*32 + 16 + gg*4 + r]));
        p1[r] = bf16s(pv1);
      }
      *(bf16x4*)(&Ps[w][lq][gg*4])      = p0;
      *(bf16x4*)(&Ps[w][lq][16 + gg*4]) = p1;
      bf16x8 pf = *(const bf16x8*)(&Ps[w][lq][gg*8]);
      int cc = sub*4 + gg;              // 16B chunk index within a V row
      bf16x8 b0 = *(const bf16x8*)((const char*)Vs + lq*128      + ((cc*16) ^ ((lq&7)<<4)));
      bf16x8 b1 = *(const bf16x8*)((const char*)Vs + (16+lq)*128 + ((cc*16) ^ (((16+lq)&7)<<4)));
      o0 = __builtin_amdgcn_mfma_f32_16x16x32_bf16(pf, b0, o0, 0, 0, 0);
      o1 = __builtin_amdgcn_mfma_f32_16x16x32_bf16(pf, b1, o1, 0, 0, 0);
      o2 = __builtin_amdgcn_mfma_f32_16x16x32_bf16(pf, ones, o2, 0, 0, 0);
    }
  }
  #pragma unroll
  for(int r=0;r<4;r++){
    int ql = gg*4 + r;
    int qg = qblk*64 + w*16 + ql;
    float mq = (float)mask[b*NL + qg];
    float sc2 = mq / o2[r];
    short* op = heads + ((size_t)(b*NL + qg))*(NHH*NDK) + h*NDK;
    op[lq]      = bf16s(o0[r]*sc2);
    op[16 + lq] = bf16s(o1[r]*sc2);
  }
}

// ---- wo: heads(bf16) x Wo^T -> Rb += (in place), stats slot 5  (T14 pipelined) ----
__global__ __launch_bounds__(256) void k_wo(const short* __restrict__ H, const short* __restrict__ Wb,
                                            short* __restrict__ Rb, float* __restrict__ stats){
  GEMM_PROLOGUE();
  const short* Asrc = H + ((size_t)(b*NL)+l0)*ND;
  const short* Bsrc = Wb + (size_t)e0*ND;
  bf16x8 ra[4], rbw[4];
  load_rows_regs(ra, Asrc, tid, 0);
  load_rows_regs(rbw, Bsrc, tid, 0);
  #pragma unroll
  for(int c=0;c<2;c++){
    __syncthreads();
    write_rows_lds(As, ra, tid);
    write_rows_lds(Bs, rbw, tid);
    if(c==0){ load_rows_regs(ra, Asrc, tid, 1); load_rows_regs(rbw, Bsrc, tid, 1); }
    __syncthreads();
    mfma_core(As, Bs, wm, wn, lq, gg, acc);
  }
  float s=0.f, ss=0.f;
  #pragma unroll
  for(int n=0;n<2;n++){
    int e = e0 + wn*32 + n*16 + lq;
    #pragma unroll
    for(int m=0;m<2;m++){
      #pragma unroll
      for(int r=0;r<4;r++){
        int l = l0 + wm*32 + m*16 + gg*4 + r;
        size_t ix = (size_t)(b*NL+l)*ND + e;
        float rr = b2f(Rb[ix]) + acc[m][n][r];
        short rs = bf16s(rr);
        Rb[ix] = rs;
        float r2 = b2f(rs);
        s += r2; ss += r2*r2;
      }
    }
  }
  stats_reduce(s, ss, stats, 5, b, blk & 7);
}

// ---- fc: LN5(Rb) x fc_w -> relu+bias, + Rb -> d_out [b][e][l] fp32  (T14 pipelined) ----
__global__ __launch_bounds__(256) void k_fc(const short* __restrict__ Rb, const short* __restrict__ gT,
                                            const short* __restrict__ bT, const float* __restrict__ stats,
                                            const short* __restrict__ Wb, const float* __restrict__ bias,
                                            float* __restrict__ out){
  GEMM_PROLOGUE();
  float mean, rstd; ln_ab(stats, 5, b, mean, rstd);
  const short* Asrc = Rb + ((size_t)(b*NL)+l0)*ND;
  const short* gs = gT + (size_t)l0*ND;
  const short* bs = bT + (size_t)l0*ND;
  const short* Bsrc = Wb + (size_t)e0*ND;
  bf16x8 rv[4], rbw[4];
  load_rows_regs(rv, Asrc, tid, 0);
  load_rows_regs(rbw, Bsrc, tid, 0);
  #pragma unroll
  for(int c=0;c<2;c++){
    __syncthreads();
    write_act_lds(As, rv, gs, bs, mean, rstd, tid, c);
    write_rows_lds(Bs, rbw, tid);
    if(c==0){ load_rows_regs(rv, Asrc, tid, 1); load_rows_regs(rbw, Bsrc, tid, 1); }
    __syncthreads();
    mfma_core(As, Bs, wm, wn, lq, gg, acc);
  }
  #pragma unroll
  for(int n=0;n<2;n++){
    int e = e0 + wn*32 + n*16 + lq;
    float bv = bias[e];
    #pragma unroll
    for(int m=0;m<2;m++){
      int lb = l0 + wm*32 + m*16 + gg*4;
      f32x4 ov;
      #pragma unroll
      for(int r=0;r<4;r++){
        float v = fmaxf(acc[m][n][r] + bv, 0.f);
        ov[r] = v + b2f(Rb[(size_t)(b*NL+lb+r)*ND + e]);
      }
      *(f32x4*)(out + (size_t)(b*ND+e)*NL + lb) = ov;
    }
  }
}

extern "C" void kernel_launch(void* const* d_in, const int* in_sizes, int n_in,
                              void* d_out, int out_size, void* d_ws, size_t ws_size,
                              hipStream_t stream){
  const float* x    = (const float*)d_in[0];
  const int*   mask = (const int*)d_in[1];
  const float* dw_w = (const float*)d_in[2];
  const float* dw_b = (const float*)d_in[3];
  const float* pw_w = (const float*)d_in[4];
  const float* pw_b = (const float*)d_in[5];
  const float* ln_g = (const float*)d_in[6];
  const float* ln_b = (const float*)d_in[7];
  const float* Wq   = (const float*)d_in[8];
  const float* Wk   = (const float*)d_in[9];
  const float* Wv   = (const float*)d_in[10];
  const float* Wo   = (const float*)d_in[11];
  const float* fc_w = (const float*)d_in[12];
  const float* fc_b = (const float*)d_in[13];

  float* ws     = (float*)d_ws;
  float* stats  = ws;                          // 98304 floats
  float* postab = ws + 98304;                  // 262144 floats
  short* Rb     = (short*)(ws + 360448);       // 4194304 bf16 [b][l][d]
  short* Yb     = (short*)(ws + 2457600);      // 4194304 bf16 (dwconv out)
  short* Hb     = (short*)(ws + 4554752);      // heads
  short* Qb     = (short*)(ws + 6651904);
  short* Kb     = (short*)(ws + 8749056);
  short* Vb     = (short*)(ws + 10846208);
  short* gT     = (short*)(ws + 12943360);     // 6*262144 bf16
  short* bT     = (short*)(ws + 13729792);
  short* Wpwb   = (short*)(ws + 14516224);     // 262144 bf16
  short* Wfcb   = (short*)(ws + 14647296);     // 65536
  short* Wob    = (short*)(ws + 14680064);     // 65536
  short* Wcat   = (short*)(ws + 14712832);     // 196608 bf16

  hipMemsetAsync(stats, 0, 98304*sizeof(float), stream);
  k_prep<<<1600,256,0,stream>>>(pw_w, fc_w, Wo, Wq, Wk, Wv, ln_g, ln_b,
                                Wpwb, Wfcb, Wob, Wcat, gT, bT, postab);
  k_posadd<<<1024,256,0,stream>>>(x, postab, Rb, stats);
  for(int i=0;i<NCONV;i++){
    k_dwconvT<<<1024,256,0,stream>>>(Rb, gT + (size_t)i*NPB, bT + (size_t)i*NPB,
                                     dw_w + i*ND*NKW, dw_b + i*ND, stats, Yb, i);
    k_pw<<<1024,256,0,stream>>>(Yb, Wpwb + (size_t)i*65536, pw_b + i*ND, Rb, stats, i+1);
  }
  k_qkvf<<<3072,256,0,stream>>>(Rb, gT + (size_t)4*NPB, bT + (size_t)4*NPB, stats, Wcat, Qb, Kb, Vb);
  k_attn<<<2048,256,0,stream>>>(Qb, Kb, Vb, mask, Hb);
  k_wo<<<1024,256,0,stream>>>(Hb, Wob, Rb, stats);
  k_fc<<<1024,256,0,stream>>>(Rb, gT + (size_t)5*NPB, bT + (size_t)5*NPB, stats, Wfcb, fc_b, (float*)d_out);
}